// Round 14
// baseline (408.828 us; speedup 1.0000x reference)
//
#include <hip/hip_runtime.h>
#include <hip/hip_cooperative_groups.h>

namespace cg = cooperative_groups;

#define BS        64
#define W_TOTAL_C 2234368
#define B_TOTAL_C 3526

__device__ __forceinline__ float silu_f(float v) {
    return v / (1.f + __expf(-v));
}

// ---------------------------------------------------------------------------
// One tile of one layer (champion R11 body, persistent-kernel safe:
// no early returns, barrier at tile end so LDS can be reused).
// Tile decode: t = (gx*NKY + ky)*64 + b.
template<int DIN, int DOUT, int KC, int NKY, int PNK, int VEC, bool FINAL,
         int WOFF, int PBOFF, int FBOFF>
__device__ __forceinline__
void tile_body(int t, int tid,
               const float* __restrict__ hin,   // x or prev partials
               float* __restrict__ outp,        // partials slice, or d_out
               const float* __restrict__ wts,
               const float* __restrict__ bias,
               float* sh)
{
    const int b  = t & 63;
    const int r  = t >> 6;
    const int ky = r % NKY;
    const int gx = r / NKY;
    const int k0 = ky * KC;

    // ---- stage h chunk (fused prev-layer reduce + bias + silu) ----
    for (int i = tid; i < KC; i += 128) {
        float s;
        if (PNK == 0) {
            s = hin[b * DIN + k0 + i];
        } else {
            s = bias[b * B_TOTAL_C + PBOFF + k0 + i];
            #pragma unroll
            for (int k = 0; k < PNK; ++k)
                s += hin[((size_t)k * BS + b) * DIN + k0 + i];
            s = silu_f(s);
        }
        sh[i] = s;
    }
    __syncthreads();

    const int o = (gx * 128 + tid) * VEC;
    if (o < DOUT) {
        float a0 = 0.f, a1 = 0.f, a2 = 0.f, a3 = 0.f;
        const float* wp = wts + (size_t)b * W_TOTAL_C + WOFF
                              + (size_t)k0 * DOUT + o;
        if (VEC == 4) {
            #pragma unroll 16
            for (int i = 0; i < KC; ++i) {
                const float hv = sh[i];
                const float4 w = *reinterpret_cast<const float4*>(wp);
                a0 = fmaf(hv, w.x, a0);
                a1 = fmaf(hv, w.y, a1);
                a2 = fmaf(hv, w.z, a2);
                a3 = fmaf(hv, w.w, a3);
                wp += DOUT;
            }
        } else {
            #pragma unroll 16
            for (int i = 0; i < KC; ++i) {
                const float hv = sh[i];
                const float2 w = *reinterpret_cast<const float2*>(wp);
                a0 = fmaf(hv, w.x, a0);
                a1 = fmaf(hv, w.y, a1);
                wp += DOUT;
            }
        }

        if (FINAL) {
            float v0 = a0 + bias[b * B_TOTAL_C + FBOFF + o];
            outp[b * DOUT + o] = tanhf(v0);
            if (o + 1 < DOUT) {
                float v1 = a1 + bias[b * B_TOTAL_C + FBOFF + o + 1];
                outp[b * DOUT + o + 1] = tanhf(v1);
            }
        } else {
            float* pp = outp + ((size_t)ky * BS + b) * DOUT + o;
            if (VEC == 4) *reinterpret_cast<float4*>(pp) = make_float4(a0, a1, a2, a3);
            else { pp[0] = a0; pp[1] = a1; }
        }
    }
    __syncthreads();   // LDS reused by next tile in the grid-stride loop
}

// ---------------------------------------------------------------------------
// Single persistent cooperative kernel: 6 phases, 5 grid-wide barriers.
// Grid = 512 blocks x 128 threads (2 blocks/CU -> co-resident everywhere).
__global__ __launch_bounds__(128)
void meta_coop(const float* __restrict__ x,
               const float* __restrict__ wts,
               const float* __restrict__ bias,
               float* __restrict__ out,
               float* p0, float* p1, float* p2, float* p3, float* p4)
{
    cg::grid_group grid = cg::this_grid();
    __shared__ float sh[512];
    const int tid = threadIdx.x;

    // P0: L0  1862->512   x -> p0    KC=133, NK=14, VEC=4   (896 tiles)
    for (int t = blockIdx.x; t < 14 * 64; t += gridDim.x)
        tile_body<1862,  512, 133, 14,  0, 4, false,       0,    0,    0>(
            t, tid, x, p0, wts, bias, sh);
    grid.sync();
    // P1: L1  512->256    p0 -> p1   KC=128, NK=4, PNK=14   (256 tiles)
    for (int t = blockIdx.x; t < 4 * 64; t += gridDim.x)
        tile_body< 512,  256, 128,  4, 14, 2, false,  953344,    0,    0>(
            t, tid, p0, p1, wts, bias, sh);
    grid.sync();
    // P2: L2  256->128    p1 -> p2   KC=64, NK=4, PNK=4     (256 tiles)
    for (int t = blockIdx.x; t < 4 * 64; t += gridDim.x)
        tile_body< 256,  128,  64,  4,  4, 2, false, 1084416,  512,    0>(
            t, tid, p1, p2, wts, bias, sh);
    grid.sync();
    // P3: L3  128->256    p2 -> p3   KC=32, NK=4, PNK=4     (256 tiles)
    for (int t = blockIdx.x; t < 4 * 64; t += gridDim.x)
        tile_body< 128,  256,  32,  4,  4, 2, false, 1117184,  768,    0>(
            t, tid, p2, p3, wts, bias, sh);
    grid.sync();
    // P4: L4  256->512    p3 -> p4   KC=64, NK=4, PNK=4, GX=2 (512 tiles)
    for (int t = blockIdx.x; t < 8 * 64; t += gridDim.x)
        tile_body< 256,  512,  64,  4,  4, 2, false, 1149952,  896,    0>(
            t, tid, p3, p4, wts, bias, sh);
    grid.sync();
    // P5: L5  512->1862   p4 -> out  full-K, PNK=4, GX=8, FINAL (512 tiles)
    for (int t = blockIdx.x; t < 8 * 64; t += gridDim.x)
        tile_body< 512, 1862, 512,  1,  4, 2, true,  1281024, 1152, 1664>(
            t, tid, p4, out, wts, bias, sh);
}

// ---------------------------------------------------------------------------
extern "C" void kernel_launch(void* const* d_in, const int* in_sizes, int n_in,
                              void* d_out, int out_size, void* d_ws, size_t ws_size,
                              hipStream_t stream)
{
    const float* x    = (const float*)d_in[0];   // [64][1862]
    const float* wts  = (const float*)d_in[1];   // [64][W_TOTAL]
    const float* bias = (const float*)d_in[2];   // [64][B_TOTAL]
    float* out = (float*)d_out;                  // [64][1862]

    // partials (floats); each slot written before read within one call
    float* p0 = (float*)d_ws;        // 14*64*512 = 458752
    float* p1 = p0 + 458752;         //  4*64*256 =  65536
    float* p2 = p1 + 65536;          //  4*64*128 =  32768
    float* p3 = p2 + 32768;          //  4*64*256 =  65536
    float* p4 = p3 + 65536;          //  4*64*512 = 131072   (~3.0 MB total)

    void* args[] = { (void*)&x, (void*)&wts, (void*)&bias, (void*)&out,
                     (void*)&p0, (void*)&p1, (void*)&p2, (void*)&p3, (void*)&p4 };
    hipLaunchCooperativeKernel((const void*)meta_coop,
                               dim3(512), dim3(128), args, 0, stream);
}